// Round 1
// baseline (714.002 us; speedup 1.0000x reference)
//
#include <hip/hip_runtime.h>

#define NROWS 4096
#define NBLK 4
#define DIN 4000
#define DE 128
#define DB 8
#define DLAT 512
#define FANIN 4136
#define KPAD 4224   // 66 * 64
#define NKT 66
#define XC 16000    // NBLK*DIN
#define OUTC 2048   // NBLK*DLAT
#define TC 192      // tail columns: 128 embed + 8 batch + 56 pad

typedef __attribute__((ext_vector_type(8))) short short8;
typedef __attribute__((ext_vector_type(4))) float floatx4;

__device__ __forceinline__ unsigned short f2bf(float f) {
    unsigned int u = __builtin_bit_cast(unsigned int, f);
    u = (u + 0x7FFFu + ((u >> 16) & 1u)) >> 16;
    return (unsigned short)u;
}

__device__ __forceinline__ void async16(const void* g, void* l) {
    __builtin_amdgcn_global_load_lds(
        (const __attribute__((address_space(1))) void*)g,
        (__attribute__((address_space(3))) void*)l, 16, 0, 0);
}

// ---------------------------------------------------------------------------
// Pack W (fp32 [4][4136][512]) -> Wp_t (bf16 [4][512][4224], n-major, K padded)
// packed k: [0,4000) = x rows, [4000,4032) = zero pad, [4032,4168) = W rows
// 4000..4135 (embed+batch), [4168,4224) = zero pad.
// Reads coalesced across n (consecutive threads = consecutive n).
// ---------------------------------------------------------------------------
__global__ void prep_w(const float* __restrict__ W, unsigned short* __restrict__ Wp) {
    int tid = blockIdx.x * 256 + threadIdx.x;   // over 4*528*512 = 1,081,344
    int n  = tid & 511;
    int t2 = tid >> 9;          // b*528 + kc
    int kc = t2 % 528;
    int b  = t2 / 528;
    unsigned short outv[8];
#pragma unroll
    for (int j = 0; j < 8; ++j) {
        int pk = kc * 8 + j;
        float v = 0.f;
        int wr = -1;
        if (pk < DIN) wr = pk;
        else if (pk >= 4032 && pk < 4168) wr = pk - 32;   // -> 4000..4135
        if (wr >= 0) v = W[((size_t)b * FANIN + wr) * DLAT + n];
        outv[j] = f2bf(v);
    }
    *reinterpret_cast<short8*>(Wp + ((size_t)(b * DLAT + n) * KPAD + kc * 8)) =
        *reinterpret_cast<const short8*>(outv);
}

// ---------------------------------------------------------------------------
// Pack tail T (bf16 [4096][4][192]): [0,128)=embed_b, [128,136)=batches, rest 0
// ---------------------------------------------------------------------------
__global__ void prep_t(const float* __restrict__ embed, const float* __restrict__ batches,
                       unsigned short* __restrict__ T) {
    int i  = blockIdx.x * 256 + threadIdx.x;   // over 4096*4*192 = 3,145,728
    int t  = i % TC;
    int nb = i / TC;       // n*4 + b
    int b  = nb & 3;
    int n  = nb >> 2;
    float v = 0.f;
    if (t < DE)            v = embed[(size_t)n * (NBLK * DE) + b * DE + t];
    else if (t < DE + DB)  v = batches[(size_t)n * DB + (t - DE)];
    T[i] = f2bf(v);
}

// ---------------------------------------------------------------------------
// Fused GEMM: per wg (mt, nt, b): rows mt*128..+128, cols nt*256..+256 of
// block b. BK=64, 66 K-tiles. A staged from x (mask/center/bf16-convert in
// regs) for k-tiles 0..62, from T via global_load_lds for 63..65. B staged
// from Wp_t via global_load_lds. 16 waves as 4(m)x4(n), wave tile 32x64,
// 2x4 MFMA frags (16x16x32 bf16), acc 32 fp32/lane.
// ---------------------------------------------------------------------------
__global__ __launch_bounds__(1024, 4) void gemm_k(
    const float* __restrict__ x, const int* __restrict__ mask,
    const float* __restrict__ mean, const float* __restrict__ bias,
    const unsigned short* __restrict__ Wp, const unsigned short* __restrict__ T,
    float* __restrict__ out) {
    __shared__ unsigned short Asm_[128 * 64];   // [row][k] bf16, 16 KB
    __shared__ unsigned short Bsm_[256 * 64];   // [n][k]  bf16, 32 KB

    int bid = blockIdx.x;
    int nt  = bid & 1;
    int mt  = (bid >> 1) & 31;
    int b   = bid >> 6;
    int tid  = threadIdx.x;
    int lane = tid & 63;
    int w    = tid >> 6;
    int wm   = w >> 2;          // 0..3 -> rows 32*wm
    int wn   = w & 3;           // 0..3 -> cols 64*wn
    int quad = lane >> 4;
    int l16  = lane & 15;
    int row0 = mt * 128;

    floatx4 acc[2][4];
#pragma unroll
    for (int m = 0; m < 2; ++m)
#pragma unroll
        for (int n2 = 0; n2 < 4; ++n2) acc[m][n2] = (floatx4){0.f, 0.f, 0.f, 0.f};

    for (int kt = 0; kt < NKT; ++kt) {
        // ---- stage A ----
        if (kt < 63) {
#pragma unroll
            for (int i = 0; i < 2; ++i) {
                int c  = i * 1024 + tid;
                int r  = c >> 4;
                int c4 = (c & 15) << 2;
                int col = kt * 64 + c4;
                int rg  = row0 + r;
                float4 v = make_float4(0.f, 0.f, 0.f, 0.f);
                if (col < DIN) {
                    size_t gi = (size_t)rg * XC + b * DIN + col;
                    float4 xv = *reinterpret_cast<const float4*>(x + gi);
                    int4   mv = *reinterpret_cast<const int4*>(mask + gi);
                    float4 me = *reinterpret_cast<const float4*>(mean + (b * DIN + col));
                    v.x = mv.x ? xv.x - me.x : 0.f;
                    v.y = mv.y ? xv.y - me.y : 0.f;
                    v.z = mv.z ? xv.z - me.z : 0.f;
                    v.w = mv.w ? xv.w - me.w : 0.f;
                }
                ushort4 pk;
                pk.x = f2bf(v.x); pk.y = f2bf(v.y); pk.z = f2bf(v.z); pk.w = f2bf(v.w);
                *reinterpret_cast<ushort4*>(&Asm_[r * 64 + c4]) = pk;
            }
        } else {
            int r = tid >> 3, k16 = tid & 7;
            int rg = row0 + r;
            const unsigned short* src =
                T + (((size_t)rg * NBLK + b) * TC + (kt - 63) * 64 + k16 * 8);
            async16(src, &Asm_[tid * 8]);
        }
        // ---- stage B (global_load_lds, 16 B per lane, wave-uniform LDS base) ----
#pragma unroll
        for (int i = 0; i < 2; ++i) {
            int c = i * 1024 + tid;
            int nl = c >> 3, k16 = c & 7;
            const unsigned short* src =
                Wp + ((size_t)(b * DLAT + nt * 256 + nl) * KPAD + kt * 64 + k16 * 8);
            async16(src, &Bsm_[c * 8]);
        }
        __syncthreads();
        // ---- MFMA ----
#pragma unroll
        for (int s = 0; s < 2; ++s) {
            short8 af[2], bfr[4];
#pragma unroll
            for (int m = 0; m < 2; ++m)
                af[m] = *reinterpret_cast<const short8*>(
                    &Asm_[(wm * 32 + m * 16 + l16) * 64 + s * 32 + quad * 8]);
#pragma unroll
            for (int n2 = 0; n2 < 4; ++n2)
                bfr[n2] = *reinterpret_cast<const short8*>(
                    &Bsm_[(wn * 64 + n2 * 16 + l16) * 64 + s * 32 + quad * 8]);
#pragma unroll
            for (int m = 0; m < 2; ++m)
#pragma unroll
                for (int n2 = 0; n2 < 4; ++n2)
                    acc[m][n2] = __builtin_amdgcn_mfma_f32_16x16x32_bf16(
                        af[m], bfr[n2], acc[m][n2], 0, 0, 0);
        }
        __syncthreads();
    }

    // ---- epilogue: bias + LeakyReLU(0.3), direct store ----
#pragma unroll
    for (int m = 0; m < 2; ++m) {
#pragma unroll
        for (int n2 = 0; n2 < 4; ++n2) {
            int col_l = wn * 64 + n2 * 16 + l16;
            int gcol  = nt * 256 + col_l;            // 0..511 within block
            float bv = bias[b * DLAT + gcol];
#pragma unroll
            for (int r = 0; r < 4; ++r) {
                int row_l = wm * 32 + m * 16 + quad * 4 + r;
                float v = acc[m][n2][r] + bv;
                v = v >= 0.f ? v : 0.3f * v;
                out[(size_t)(row0 + row_l) * OUTC + b * DLAT + gcol] = v;
            }
        }
    }
}

extern "C" void kernel_launch(void* const* d_in, const int* in_sizes, int n_in,
                              void* d_out, int out_size, void* d_ws, size_t ws_size,
                              hipStream_t stream) {
    const float* x       = (const float*)d_in[0];
    const int*   mask    = (const int*)d_in[1];
    const float* embed   = (const float*)d_in[2];
    const float* batches = (const float*)d_in[3];
    const float* mean    = (const float*)d_in[4];
    const float* W       = (const float*)d_in[5];
    const float* bias    = (const float*)d_in[6];
    float* out = (float*)d_out;

    unsigned short* Wp = (unsigned short*)d_ws;                       // 4*512*4224 bf16 = 17.3 MB
    unsigned short* T  = Wp + (size_t)NBLK * DLAT * KPAD;             // 4096*4*192 bf16 = 6.3 MB

    prep_w<<<dim3(4224), dim3(256), 0, stream>>>(W, Wp);
    prep_t<<<dim3(12288), dim3(256), 0, stream>>>(embed, batches, T);
    gemm_k<<<dim3(256), dim3(1024), 0, stream>>>(x, mask, mean, bias, Wp, T, out);
}